// Round 2
// baseline (668.854 us; speedup 1.0000x reference)
//
#include <hip/hip_runtime.h>

#define BLK 256

__device__ __forceinline__ float lrelu(float x) {
    return x > 0.0f ? x : 0.01f * x;
}

__device__ __forceinline__ float pick4(const float a[4], int f) {
    float r = a[0];
    r = (f == 1) ? a[1] : r;
    r = (f == 2) ? a[2] : r;
    r = (f == 3) ? a[3] : r;
    return r;
}

// Bilinear lookup of one level (fpl=4 features) for base_res=16 grids.
// Table is float4-per-cell; level l occupies [256*(4^l-1)/3, ...) float4s, res=16<<l.
__device__ __forceinline__ void bilerp(const float4* __restrict__ tbl, float u, float v,
                                       int l, float out[4]) {
    const int res = 16 << l;
    const float scale = (float)(res - 1);
    float px = u * scale + 0.5f;
    float py = v * scale + 0.5f;
    float fx = floorf(px), fy = floorf(py);
    float wx = px - fx, wy = py - fy;
    int ix0 = (int)fx;
    int iy0 = (int)fy;
    ix0 = min(max(ix0, 0), res - 1);
    iy0 = min(max(iy0, 0), res - 1);
    int ix1 = min(ix0 + 1, res - 1);
    int iy1 = min(iy0 + 1, res - 1);
    unsigned base = ((1u << (2 * l)) - 1u) / 3u * 256u;  // float4 units, exact
    float4 f00 = tbl[base + iy0 * res + ix0];
    float4 f10 = tbl[base + iy0 * res + ix1];
    float4 f01 = tbl[base + iy1 * res + ix0];
    float4 f11 = tbl[base + iy1 * res + ix1];
    float owx = 1.0f - wx, owy = 1.0f - wy;
    out[0] = (f00.x * owx + f10.x * wx) * owy + (f01.x * owx + f11.x * wx) * wy;
    out[1] = (f00.y * owx + f10.y * wx) * owy + (f01.y * owx + f11.y * wx) * wy;
    out[2] = (f00.z * owx + f10.z * wx) * owy + (f01.z * owx + f11.z * wx) * wy;
    out[3] = (f00.w * owx + f10.w * wx) * owy + (f01.w * owx + f11.w * wx) * wy;
}

// Reproduces dense_grid_encode + take_along_axis: only the (at most) two levels
// covered by cols = trunc((L-1-clipped)*4 + j), j=0..3 are evaluated.
__device__ __forceinline__ void grid_select(const float4* __restrict__ tbl, float u, float v,
                                            float mips, int L, float out[4]) {
    const float Lm1 = (float)(L - 1);
    float clipped = fminf(mips, Lm1);
    float c0 = (Lm1 - clipped) * 4.0f;
    // Block fma-contraction into the adds below: the int-cast is a genuine
    // discontinuity and must match JAX's mul-then-add fp32 rounding exactly.
    asm volatile("" : "+v"(c0));
    int col0 = (int)c0;
    int col1 = (int)(c0 + 1.0f);
    int col2 = (int)(c0 + 2.0f);
    int col3 = (int)(c0 + 3.0f);
    int lA = col0 >> 2;
    int lB = col3 >> 2;   // == lA or lA+1
    float A[4], Bv[4];
    bilerp(tbl, u, v, lA, A);
    bilerp(tbl, u, v, lB, Bv);  // redundant when lA==lB (cache-hit), keeps control flow uniform
    int cols[4] = {col0, col1, col2, col3};
    #pragma unroll
    for (int j = 0; j < 4; ++j) {
        int lj = cols[j] >> 2;
        int fj = cols[j] & 3;
        float va = pick4(A, fj);
        float vb = pick4(Bv, fj);
        out[j] = (lj == lA) ? va : vb;
    }
}

__global__ __launch_bounds__(BLK) void tcnn_fwd(
    const float* __restrict__ x,
    const float4* __restrict__ g0,
    const float4* __restrict__ g1,
    const float* __restrict__ Win,   // (33,64) row-major
    const float* __restrict__ Wh,    // (64,64) row-major
    const float* __restrict__ Wout,  // (64,11) row-major
    float* __restrict__ out,         // (B,11)
    int npts)
{
    int p = blockIdx.x * BLK + threadIdx.x;
    if (p >= npts) return;

    float xu = x[p * 3 + 0];
    float xv = x[p * 3 + 1];
    float lod = x[p * 3 + 2];
    float u = xu - floorf(xu);   // remainder(x, 1.0)
    float v = xv - floorf(xv);
    float mips = lod * 7.0f;     // NUM_LODS - NUM_SAMPLED_LODS = 7

    float inp[33];
    // triangle-wave PE: 12 freqs for u, then 12 for v
    #pragma unroll
    for (int f = 0; f < 12; ++f) {
        float fr = (float)(1 << f);
        float xf = u * fr;
        inp[f] = fabsf(xf - floorf(xf + 0.5f)) * 4.0f - 1.0f;
        float yf = v * fr;
        inp[12 + f] = fabsf(yf - floorf(yf + 0.5f)) * 4.0f - 1.0f;
    }
    grid_select(g0, u, v, mips, 8, &inp[24]);
    grid_select(g1, u, v, mips, 7, &inp[28]);
    inp[32] = lod;

    // ---- layer 1: 33 -> 64 ----
    float h1[64];
    #pragma unroll
    for (int j = 0; j < 64; ++j) h1[j] = 0.0f;
    #pragma unroll
    for (int i = 0; i < 33; ++i) {
        float a = inp[i];
        const float* wr = Win + i * 64;
        #pragma unroll
        for (int j = 0; j < 64; ++j) h1[j] = fmaf(a, wr[j], h1[j]);
    }
    #pragma unroll
    for (int j = 0; j < 64; ++j) h1[j] = lrelu(h1[j]);

    // ---- layer 2: 64 -> 64 ----
    float h2[64];
    #pragma unroll
    for (int j = 0; j < 64; ++j) h2[j] = 0.0f;
    #pragma unroll
    for (int i = 0; i < 64; ++i) {
        float a = h1[i];
        const float* wr = Wh + i * 64;
        #pragma unroll
        for (int j = 0; j < 64; ++j) h2[j] = fmaf(a, wr[j], h2[j]);
    }
    #pragma unroll
    for (int j = 0; j < 64; ++j) h2[j] = lrelu(h2[j]);

    // ---- layer 3: 64 -> 11 ----
    float o[11];
    #pragma unroll
    for (int j = 0; j < 11; ++j) o[j] = 0.0f;
    #pragma unroll
    for (int i = 0; i < 64; ++i) {
        float a = h2[i];
        const float* wr = Wout + i * 11;
        #pragma unroll
        for (int j = 0; j < 11; ++j) o[j] = fmaf(a, wr[j], o[j]);
    }
    float* op = out + (size_t)p * 11;
    #pragma unroll
    for (int j = 0; j < 11; ++j) op[j] = lrelu(o[j]);
}

extern "C" void kernel_launch(void* const* d_in, const int* in_sizes, int n_in,
                              void* d_out, int out_size, void* d_ws, size_t ws_size,
                              hipStream_t stream) {
    const float* x = (const float*)d_in[0];
    const float4* g0 = (const float4*)d_in[1];
    const float4* g1 = (const float4*)d_in[2];
    const float* Win = (const float*)d_in[3];
    const float* Wh = (const float*)d_in[4];
    const float* Wout = (const float*)d_in[5];
    float* out = (float*)d_out;
    int npts = in_sizes[0] / 3;
    int grid = (npts + BLK - 1) / BLK;
    tcnn_fwd<<<grid, BLK, 0, stream>>>(x, g0, g1, Win, Wh, Wout, out, npts);
}

// Round 3
// 275.673 us; speedup vs baseline: 2.4263x; 2.4263x over previous
//
#include <hip/hip_runtime.h>

typedef float f32x4 __attribute__((ext_vector_type(4)));
typedef __bf16 bf16x8 __attribute__((ext_vector_type(8)));

#define PERM __builtin_amdgcn_perm

static __device__ __forceinline__ bf16x8 as_bf(uint4 v) {
    union { uint4 u; bf16x8 b; } c; c.u = v; return c.b;
}

static __device__ __forceinline__ float lrelu(float x) { return x > 0.0f ? x : 0.01f * x; }

// f32 -> packed (bf16_hi << 16) | bf16_lo, both RTN-even. v == hi + lo exactly up to
// bf16(lo) rounding (~2^-18 relative).
static __device__ __forceinline__ unsigned pack_hilo(float v) {
    unsigned b = __float_as_uint(v);
    unsigned hi = (b + 0x7FFFu + ((b >> 16) & 1u)) >> 16;
    float hif = __uint_as_float(hi << 16);
    float lof = v - hif;
    unsigned lb = __float_as_uint(lof);
    unsigned lo = (lb + 0x7FFFu + ((lb >> 16) & 1u)) >> 16;
    return (hi << 16) | lo;
}

// 8 packed u32 (k ascending) -> bf16x8 hi-frag and lo-frag (as 4 u32 each).
static __device__ __forceinline__ void unpack_frag(uint4 p0, uint4 p1, uint4& hi, uint4& lo) {
    hi.x = PERM(p0.y, p0.x, 0x07060302u);
    hi.y = PERM(p0.w, p0.z, 0x07060302u);
    hi.z = PERM(p1.y, p1.x, 0x07060302u);
    hi.w = PERM(p1.w, p1.z, 0x07060302u);
    lo.x = PERM(p0.y, p0.x, 0x05040100u);
    lo.y = PERM(p0.w, p0.z, 0x05040100u);
    lo.z = PERM(p1.y, p1.x, 0x05040100u);
    lo.w = PERM(p1.w, p1.z, 0x05040100u);
}

// Weight B-frag: unswizzled [n][k] row, q points at element (n, kbase+8*g).
static __device__ __forceinline__ void read_frag_w(const unsigned* q, uint4& hi, uint4& lo) {
    uint4 p0 = *(const uint4*)(q);
    uint4 p1 = *(const uint4*)(q + 4);
    unpack_frag(p0, p1, hi, lo);
}

// Activation A-frag: swizzled [r][64] rows: element k lives at chunk (k>>2)^(r&15).
static __device__ __forceinline__ void read_frag_a(const unsigned* actb, int r, int kbase, int g,
                                                   uint4& hi, uint4& lo) {
    const unsigned* row = actb + r * 64;
    int cb = (kbase >> 2) + 2 * g;
    int rx = r & 15;
    uint4 p0 = *(const uint4*)(row + ((cb ^ rx) << 2));
    uint4 p1 = *(const uint4*)(row + (((cb + 1) ^ rx) << 2));
    unpack_frag(p0, p1, hi, lo);
}

static __device__ __forceinline__ void act_store(unsigned* actb, int row, int col, unsigned val) {
    int pos = row * 64 + ((((col >> 2) ^ (row & 15)) << 2) | (col & 3));
    actb[pos] = val;
}

// D = A*B + C with split-bf16 operands (hi*hi + lo*hi + hi*lo; lo*lo dropped).
static __device__ __forceinline__ f32x4 mfma3(const uint4& ah, const uint4& al,
                                              const uint4& bh, const uint4& bl, f32x4 c) {
    c = __builtin_amdgcn_mfma_f32_16x16x32_bf16(as_bf(ah), as_bf(bh), c, 0, 0, 0);
    c = __builtin_amdgcn_mfma_f32_16x16x32_bf16(as_bf(al), as_bf(bh), c, 0, 0, 0);
    c = __builtin_amdgcn_mfma_f32_16x16x32_bf16(as_bf(ah), as_bf(bl), c, 0, 0, 0);
    return c;
}

static __device__ __forceinline__ void bilerp(const float4* __restrict__ tbl, float u, float v,
                                              int l, float out[4]) {
    const int res = 16 << l;
    const float scale = (float)(res - 1);
    float px = u * scale + 0.5f;
    float py = v * scale + 0.5f;
    float fx = floorf(px), fy = floorf(py);
    float wx = px - fx, wy = py - fy;
    int ix0 = min(max((int)fx, 0), res - 1);
    int iy0 = min(max((int)fy, 0), res - 1);
    int ix1 = min(ix0 + 1, res - 1);
    int iy1 = min(iy0 + 1, res - 1);
    unsigned base = (0x55555555u & ((1u << (2 * l)) - 1u)) * 256u;  // 256*(4^l-1)/3
    float4 f00 = tbl[base + iy0 * res + ix0];
    float4 f10 = tbl[base + iy0 * res + ix1];
    float4 f01 = tbl[base + iy1 * res + ix0];
    float4 f11 = tbl[base + iy1 * res + ix1];
    float owx = 1.0f - wx, owy = 1.0f - wy;
    out[0] = (f00.x * owx + f10.x * wx) * owy + (f01.x * owx + f11.x * wx) * wy;
    out[1] = (f00.y * owx + f10.y * wx) * owy + (f01.y * owx + f11.y * wx) * wy;
    out[2] = (f00.z * owx + f10.z * wx) * owy + (f01.z * owx + f11.z * wx) * wy;
    out[3] = (f00.w * owx + f10.w * wx) * owy + (f01.w * owx + f11.w * wx) * wy;
}

static __device__ __forceinline__ void grid_select(const float4* __restrict__ tbl, float u, float v,
                                                   float mips, float Lm1, float out[4]) {
    float clipped = fminf(mips, Lm1);
    float c0 = (Lm1 - clipped) * 4.0f;
    // Pin mul-then-add rounding (the int cast is a genuine discontinuity; must match JAX).
    asm volatile("" : "+v"(c0));
    int col0 = (int)c0;
    int col1 = (int)(c0 + 1.0f);
    int col2 = (int)(c0 + 2.0f);
    int col3 = (int)(c0 + 3.0f);
    int lA = col0 >> 2;
    int lB = col3 >> 2;
    float A[4], Bv[4];
    bilerp(tbl, u, v, lA, A);
    bilerp(tbl, u, v, lB, Bv);
    int cols[4] = {col0, col1, col2, col3};
    #pragma unroll
    for (int j = 0; j < 4; ++j) {
        int lj = cols[j] >> 2;
        int fj = cols[j] & 3;
        float va = A[0];
        va = (fj == 1) ? A[1] : va;
        va = (fj == 2) ? A[2] : va;
        va = (fj == 3) ? A[3] : va;
        float vb = Bv[0];
        vb = (fj == 1) ? Bv[1] : vb;
        vb = (fj == 2) ? Bv[2] : vb;
        vb = (fj == 3) ? Bv[3] : vb;
        out[j] = (lj == lA) ? va : vb;
    }
}

// LDS carve (u32 units):
//   winT  [64n][32k]  2048   packed hi/lo of W_in[k][n], k<32
//   whT   [64n][64k]  4096
//   woutT [16n][64k]  1024   (n>=11 zero)
//   lodw  [64]          64   f32 W_in[32][n]
//   lodv  [4][32]      128   f32 per-wave lod values
//   act   [4][32][64] 8192   per-wave activation buffer, chunk-XOR swizzled
#define LDS_U32 (2048 + 4096 + 1024 + 64 + 128 + 8192)

__global__ __launch_bounds__(256, 2) void tcnn_fwd(
    const float* __restrict__ x,
    const float4* __restrict__ g0,
    const float4* __restrict__ g1,
    const float* __restrict__ Win,   // (33,64)
    const float* __restrict__ Wh,    // (64,64)
    const float* __restrict__ Wout,  // (64,11)
    float* __restrict__ out,
    int npts)
{
    extern __shared__ unsigned smem[];
    unsigned* s_winT  = smem;
    unsigned* s_whT   = s_winT + 2048;
    unsigned* s_woutT = s_whT + 4096;
    float*    s_lodw  = (float*)(s_woutT + 1024);
    float*    s_lodv  = s_lodw + 64;
    unsigned* s_act   = (unsigned*)(s_lodv + 128);

    const int tid = threadIdx.x;

    // ---- one-time weight prep ----
    for (int e = tid; e < 2048; e += 256) {        // WinT
        int n = e >> 5, k = e & 31;
        s_winT[n * 32 + k] = pack_hilo(Win[k * 64 + n]);
    }
    for (int e = tid; e < 4096; e += 256) {        // WhT
        int n = e >> 6, k = e & 63;
        s_whT[n * 64 + k] = pack_hilo(Wh[k * 64 + n]);
    }
    for (int e = tid; e < 1024; e += 256) {        // WoutT (pad n 11..15 with 0)
        int n = e >> 6, k = e & 63;
        float w = (n < 11) ? Wout[k * 11 + n] : 0.0f;
        s_woutT[n * 64 + k] = pack_hilo(w);
    }
    if (tid < 64) s_lodw[tid] = Win[32 * 64 + tid];
    __syncthreads();

    const int wv = tid >> 6;
    const int l = tid & 63;
    const int g = l >> 4;       // 4-row group within 16x16 tile
    const int m = l & 15;       // col within tile
    const int half = l >> 5;
    const int p = l & 31;       // point within wave chunk

    unsigned* act = s_act + wv * 2048;
    float* lodv = s_lodv + wv * 32;

    // ---- hoist all weight B-fragments into registers ----
    uint4 w1h[4], w1l[4];
    #pragma unroll
    for (int Nt = 0; Nt < 4; ++Nt)
        read_frag_w(s_winT + (Nt * 16 + m) * 32 + 8 * g, w1h[Nt], w1l[Nt]);
    uint4 w2h[4][2], w2l[4][2];
    #pragma unroll
    for (int Nt = 0; Nt < 4; ++Nt)
        #pragma unroll
        for (int ks = 0; ks < 2; ++ks)
            read_frag_w(s_whT + (Nt * 16 + m) * 64 + ks * 32 + 8 * g, w2h[Nt][ks], w2l[Nt][ks]);
    uint4 w3h[2], w3l[2];
    #pragma unroll
    for (int ks = 0; ks < 2; ++ks)
        read_frag_w(s_woutT + m * 64 + ks * 32 + 8 * g, w3h[ks], w3l[ks]);

    for (int cb = (blockIdx.x * 4 + wv) * 32; cb + 31 < npts; cb += gridDim.x * 128) {
        // ---- feature build: lane p does u-half, lane p+32 does v-half of point cb+p ----
        int gp = cb + p;
        float xu = x[gp * 3 + 0];
        float xv = x[gp * 3 + 1];
        float xl = x[gp * 3 + 2];
        float u = xu - floorf(xu);
        float vv = xv - floorf(xv);
        float coord = half ? vv : u;
        #pragma unroll
        for (int f = 0; f < 12; ++f) {
            float fr = (float)(1 << f);
            float xf = coord * fr;
            float t = fabsf(xf - floorf(xf + 0.5f)) * 4.0f - 1.0f;
            act_store(act, p, half * 12 + f, pack_hilo(t));
        }
        {
            const float4* tbl = half ? g1 : g0;
            float Lm1 = half ? 6.0f : 7.0f;
            float mips = xl * 7.0f;
            float gf[4];
            grid_select(tbl, u, vv, mips, Lm1, gf);
            #pragma unroll
            for (int j = 0; j < 4; ++j)
                act_store(act, p, 24 + half * 4 + j, pack_hilo(gf[j]));
        }
        if (half) lodv[p] = xl;
        __builtin_amdgcn_wave_barrier();

        // ---- layer 1: K=32 MFMA + exact f32 rank-1 lod update ----
        uint4 a1h[2], a1l[2];
        #pragma unroll
        for (int Mt = 0; Mt < 2; ++Mt)
            read_frag_a(act, Mt * 16 + m, 0, g, a1h[Mt], a1l[Mt]);
        f32x4 acc1[2][4];
        #pragma unroll
        for (int Mt = 0; Mt < 2; ++Mt)
            #pragma unroll
            for (int Nt = 0; Nt < 4; ++Nt)
                acc1[Mt][Nt] = (f32x4){0.f, 0.f, 0.f, 0.f};
        #pragma unroll
        for (int Nt = 0; Nt < 4; ++Nt)
            #pragma unroll
            for (int Mt = 0; Mt < 2; ++Mt)
                acc1[Mt][Nt] = mfma3(a1h[Mt], a1l[Mt], w1h[Nt], w1l[Nt], acc1[Mt][Nt]);
        float lv[2][4];
        #pragma unroll
        for (int Mt = 0; Mt < 2; ++Mt)
            #pragma unroll
            for (int i = 0; i < 4; ++i)
                lv[Mt][i] = lodv[Mt * 16 + 4 * g + i];
        #pragma unroll
        for (int Nt = 0; Nt < 4; ++Nt) {
            float wl = s_lodw[Nt * 16 + m];
            #pragma unroll
            for (int Mt = 0; Mt < 2; ++Mt)
                #pragma unroll
                for (int i = 0; i < 4; ++i)
                    acc1[Mt][Nt][i] = fmaf(lv[Mt][i], wl, acc1[Mt][Nt][i]);
        }
        __builtin_amdgcn_wave_barrier();
        #pragma unroll
        for (int Mt = 0; Mt < 2; ++Mt)
            #pragma unroll
            for (int Nt = 0; Nt < 4; ++Nt)
                #pragma unroll
                for (int i = 0; i < 4; ++i)
                    act_store(act, Mt * 16 + 4 * g + i, Nt * 16 + m,
                              pack_hilo(lrelu(acc1[Mt][Nt][i])));
        __builtin_amdgcn_wave_barrier();

        // ---- layer 2: K=64 ----
        f32x4 acc2[2][4];
        #pragma unroll
        for (int Mt = 0; Mt < 2; ++Mt)
            #pragma unroll
            for (int Nt = 0; Nt < 4; ++Nt)
                acc2[Mt][Nt] = (f32x4){0.f, 0.f, 0.f, 0.f};
        #pragma unroll
        for (int Mt = 0; Mt < 2; ++Mt) {
            uint4 ah[2], al[2];
            #pragma unroll
            for (int ks = 0; ks < 2; ++ks)
                read_frag_a(act, Mt * 16 + m, ks * 32, g, ah[ks], al[ks]);
            #pragma unroll
            for (int Nt = 0; Nt < 4; ++Nt)
                #pragma unroll
                for (int ks = 0; ks < 2; ++ks)
                    acc2[Mt][Nt] = mfma3(ah[ks], al[ks], w2h[Nt][ks], w2l[Nt][ks], acc2[Mt][Nt]);
        }
        __builtin_amdgcn_wave_barrier();
        #pragma unroll
        for (int Mt = 0; Mt < 2; ++Mt)
            #pragma unroll
            for (int Nt = 0; Nt < 4; ++Nt)
                #pragma unroll
                for (int i = 0; i < 4; ++i)
                    act_store(act, Mt * 16 + 4 * g + i, Nt * 16 + m,
                              pack_hilo(lrelu(acc2[Mt][Nt][i])));
        __builtin_amdgcn_wave_barrier();

        // ---- layer 3: K=64, N=16 (11 valid) ----
        f32x4 acc3[2];
        acc3[0] = (f32x4){0.f, 0.f, 0.f, 0.f};
        acc3[1] = (f32x4){0.f, 0.f, 0.f, 0.f};
        #pragma unroll
        for (int Mt = 0; Mt < 2; ++Mt) {
            uint4 ah[2], al[2];
            #pragma unroll
            for (int ks = 0; ks < 2; ++ks)
                read_frag_a(act, Mt * 16 + m, ks * 32, g, ah[ks], al[ks]);
            #pragma unroll
            for (int ks = 0; ks < 2; ++ks)
                acc3[Mt] = mfma3(ah[ks], al[ks], w3h[ks], w3l[ks], acc3[Mt]);
        }
        #pragma unroll
        for (int Mt = 0; Mt < 2; ++Mt)
            #pragma unroll
            for (int i = 0; i < 4; ++i) {
                int row = Mt * 16 + 4 * g + i;
                float val = lrelu(acc3[Mt][i]);
                if (m < 11) out[(size_t)(cb + row) * 11 + m] = val;
            }
        __builtin_amdgcn_wave_barrier();
    }
}

extern "C" void kernel_launch(void* const* d_in, const int* in_sizes, int n_in,
                              void* d_out, int out_size, void* d_ws, size_t ws_size,
                              hipStream_t stream) {
    const float* x = (const float*)d_in[0];
    const float4* g0 = (const float4*)d_in[1];
    const float4* g1 = (const float4*)d_in[2];
    const float* Win = (const float*)d_in[3];
    const float* Wh = (const float*)d_in[4];
    const float* Wout = (const float*)d_in[5];
    float* out = (float*)d_out;
    int npts = in_sizes[0] / 3;
    tcnn_fwd<<<512, 256, LDS_U32 * 4, stream>>>(x, g0, g1, Win, Wh, Wout, out, npts);
}